// Round 8
// baseline (121.881 us; speedup 1.0000x reference)
//
#include <hip/hip_runtime.h>
#include <stdint.h>

// Fused BSQ: recon = sign(x @ Wp + bp) @ Wr + br   (L2-normalize is sign-invariant)
// x: [65536][512] f32, Wp: [512][16], bp: [16], Wr: [16][512], br: [512]
//
// Round-8: 2-wave blocks, pk-FMA, conflict-free LDS, full-grid residency.
//  - Wave h owns c-half [h*256, h*256+256). Lane (a=l>>2, b=l&3) covers
//    16 c (strided: cbase + 64k + e) x 4 consecutive d (4b..4b+3).
//  - x staged via 4-slot/1-row global_load_lds ring (1 DMA instr/row/wave),
//    per-wave counted WAITV(3), zero barriers in phase A.
//  - Dot/recon in v2f (v_pk_fma_f32): dot 32 pk, recon 32 pk + 1 b128 store.
//  - In-wave butterfly (shfl_xor 4/8/16/32) -> one b128 zbuf write/row;
//    ONE barrier/block; phase B: 2 conflict-free b32 reads + ballot -> mask.
//  - 2048 blocks x 2 waves = 16 waves/CU = 4/EU, LDS 12.5 KB -> ALL blocks
//    resident (amdgpu_waves_per_eu(4,4) pins the register budget at 128;
//    round-5 showed min-only launch_bounds lets the allocator spill at 64).
//  - Rare (~2%) exact-f64 fixup post-loop, uniform, matched barriers.
//    Reference signs are f64-exact: rounds 1-7 absmax 0.0.

#define ROWS   65536
#define TILE   32
#define BLOCKS (ROWS / TILE)   // 2048
#define TAU    1e-3f
#define RING   4

#define BAR()    asm volatile("s_waitcnt lgkmcnt(0)\n\ts_barrier" ::: "memory")
#define WAITV(N) asm volatile("s_waitcnt vmcnt(" #N ")" ::: "memory")
#define WAITL()  asm volatile("s_waitcnt lgkmcnt(0)" ::: "memory")

typedef const __attribute__((address_space(1))) void* gas1_t;
typedef __attribute__((address_space(3))) void*       las3_t;
typedef float v2f __attribute__((ext_vector_type(2)));

__global__ __launch_bounds__(128)
__attribute__((amdgpu_waves_per_eu(4, 4)))
void bsq_fused(const float* __restrict__ x,
               const float* __restrict__ Wp,
               const float* __restrict__ bp,
               const float* __restrict__ Wr,
               const float* __restrict__ br,
               float* __restrict__ out)
{
    const int tid = threadIdx.x;
    const int h   = tid >> 6;      // wave: c-half
    const int l   = tid & 63;
    const int a   = l >> 2;        // 0..15: c-subgroup
    const int b   = l & 3;         // d-quad: d = 4b+q
    const int dg  = l & 15;

    __shared__ __align__(16) float  xl[RING][512];     // 8 KB x ring
    __shared__ __align__(16) float  zbuf[TILE][2][16]; // 4 KB half-row sums
    __shared__ __align__(16) double zb64[2][16];       // fixup exchange

    const int row0  = blockIdx.x * TILE;
    const int cbase = h * 256 + a * 4;   // lane's c chunks at cbase + 64k

    // ---- phase-A weights: v2f over c-pairs, d-quad per lane ----
    v2f wpq[4][8];   // wpq[q][2k+p] = (Wp[c0][4b+q], Wp[c0+1][4b+q])
#pragma unroll
    for (int k = 0; k < 4; ++k)
#pragma unroll
        for (int p = 0; p < 2; ++p) {
            const float* w0 = Wp + (cbase + 64 * k + 2 * p) * 16 + 4 * b;
#pragma unroll
            for (int q = 0; q < 4; ++q)
                wpq[q][2 * k + p] = (v2f){ w0[q], w0[16 + q] };
        }
    const float bpf = bp[dg];

    const float* xsrc = x + (size_t)row0 * 512 + h * 256 + l * 4;

    auto stage = [&](int r) {   // wave h DMAs its 1 KB half of row r
        __builtin_amdgcn_global_load_lds((gas1_t)(xsrc + (size_t)r * 512),
            (las3_t)(&xl[r & (RING - 1)][h * 256]), 16, 0, 0);
    };

    auto dot_row = [&](int r, bool prefetch) {
        const float* bx = &xl[r & (RING - 1)][cbase];
        float4 xr[4];
#pragma unroll
        for (int k = 0; k < 4; ++k) xr[k] = *(const float4*)(bx + 64 * k);

        v2f a0 = {0.f, 0.f}, a1 = {0.f, 0.f}, a2 = {0.f, 0.f}, a3 = {0.f, 0.f};
#pragma unroll
        for (int k = 0; k < 4; ++k) {
            const v2f xlo = { xr[k].x, xr[k].y }, xhi = { xr[k].z, xr[k].w };
            a0 += wpq[0][2 * k] * xlo;  a0 += wpq[0][2 * k + 1] * xhi;
            a1 += wpq[1][2 * k] * xlo;  a1 += wpq[1][2 * k + 1] * xhi;
            a2 += wpq[2][2 * k] * xlo;  a2 += wpq[2][2 * k + 1] * xhi;
            a3 += wpq[3][2 * k] * xlo;  a3 += wpq[3][2 * k + 1] * xhi;
        }
        WAITL();                        // slot's ds_reads retired
        if (prefetch) stage(r + RING);  // refill same slot, 4 rows ahead

        float z0 = a0.x + a0.y, z1 = a1.x + a1.y,
              z2 = a2.x + a2.y, z3 = a3.x + a3.y;
#pragma unroll
        for (int off = 4; off <= 32; off <<= 1) {   // reduce over a (bits 2-5)
            z0 += __shfl_xor(z0, off, 64);
            z1 += __shfl_xor(z1, off, 64);
            z2 += __shfl_xor(z2, off, 64);
            z3 += __shfl_xor(z3, off, 64);
        }
        if (l < 4)   // lane b=l holds d = 4l+q
            *(float4*)&zbuf[r][h][4 * l] = make_float4(z0, z1, z2, z3);
    };

    // ================= Phase A: signs (no barriers) =================
#pragma unroll
    for (int r = 0; r < RING; ++r) stage(r);

#pragma unroll 1
    for (int r0 = 0; r0 < TILE - RING; r0 += 4) {
#pragma unroll
        for (int rr = 0; rr < 4; ++rr) { WAITV(3); dot_row(r0 + rr, true); }
    }
    WAITV(3); dot_row(TILE - 4, false);
    WAITV(2); dot_row(TILE - 3, false);
    WAITV(1); dot_row(TILE - 2, false);
    WAITV(0); dot_row(TILE - 1, false);

    BAR();   // zbuf visible (lgkm-only; vmcnt already 0)

    // ---- phase-B weights (wpq dead; disjoint lifetime) ----
    float4 wr4[16];   // Wr[d][tid*4 .. +3]
#pragma unroll
    for (int d = 0; d < 16; ++d) wr4[d] = ((const float4*)Wr)[d * 128 + tid];
    const float4 br4v = ((const float4*)br)[tid];

    // ============ Phase B: reduce + recon (barrier-free) ============
    uint32_t ambmask = 0;   // block-uniform (built from ballots of uniform z)
#pragma unroll 4
    for (int r = 0; r < TILE; ++r) {
        const float z = zbuf[r][0][dg] + zbuf[r][1][dg] + bpf;
        if (__ballot(fabsf(z) < TAU)) ambmask |= (1u << r);
        const int m = (int)(__ballot(z >= 0.0f) & 0xFFFFull);

        v2f o01 = { br4v.x, br4v.y }, o23 = { br4v.z, br4v.w };
#pragma unroll
        for (int d = 0; d < 16; ++d) {
            const float s = ((m >> d) & 1) ? 1.0f : -1.0f;
            const v2f sv = { s, s };
            o01 += ((const v2f*)&wr4[d])[0] * sv;
            o23 += ((const v2f*)&wr4[d])[1] * sv;
        }
        ((float4*)out)[(size_t)(row0 + r) * 128 + tid] =
            make_float4(o01.x, o01.y, o23.x, o23.y);
    }

    // ===== Fixup: rare exact-f64 redo; uniform loop, matched barriers =====
    const double bpd = (double)bpf;
#pragma unroll 1
    while (ambmask) {
        const int r = __ffs(ambmask) - 1;
        ambmask &= ambmask - 1;
        const int row = row0 + r;

        double d0 = 0.0, d1 = 0.0, d2 = 0.0, d3 = 0.0;
#pragma unroll
        for (int k = 0; k < 4; ++k) {
            const float4 xf = *(const float4*)(x + (size_t)row * 512 + cbase + 64 * k);
            const float* w0 = Wp + (cbase + 64 * k) * 16 + 4 * b;
            const float xe[4] = { xf.x, xf.y, xf.z, xf.w };
#pragma unroll
            for (int e = 0; e < 4; ++e) {
                const double xd = (double)xe[e];
                d0 = fma(xd, (double)w0[e * 16 + 0], d0);
                d1 = fma(xd, (double)w0[e * 16 + 1], d1);
                d2 = fma(xd, (double)w0[e * 16 + 2], d2);
                d3 = fma(xd, (double)w0[e * 16 + 3], d3);
            }
        }
#pragma unroll
        for (int off = 4; off <= 32; off <<= 1) {
            d0 += __shfl_xor(d0, off, 64);
            d1 += __shfl_xor(d1, off, 64);
            d2 += __shfl_xor(d2, off, 64);
            d3 += __shfl_xor(d3, off, 64);
        }
        if (l < 4) {
            zb64[h][4 * l + 0] = d0;  zb64[h][4 * l + 1] = d1;
            zb64[h][4 * l + 2] = d2;  zb64[h][4 * l + 3] = d3;
        }
        BAR();
        const double zd = zb64[0][dg] + zb64[1][dg] + bpd;
        const int m = (int)(__ballot(zd >= 0.0) & 0xFFFFull);
        BAR();   // zb64 reads retired before next fixup row's rewrite

        v2f o01 = { br4v.x, br4v.y }, o23 = { br4v.z, br4v.w };
#pragma unroll
        for (int d = 0; d < 16; ++d) {
            const float s = ((m >> d) & 1) ? 1.0f : -1.0f;
            const v2f sv = { s, s };
            o01 += ((const v2f*)&wr4[d])[0] * sv;
            o23 += ((const v2f*)&wr4[d])[1] * sv;
        }
        ((float4*)out)[(size_t)row * 128 + tid] =
            make_float4(o01.x, o01.y, o23.x, o23.y);
    }
}

extern "C" void kernel_launch(void* const* d_in, const int* in_sizes, int n_in,
                              void* d_out, int out_size, void* d_ws, size_t ws_size,
                              hipStream_t stream) {
    const float* x  = (const float*)d_in[0];
    const float* Wp = (const float*)d_in[1];
    const float* bp = (const float*)d_in[2];
    const float* Wr = (const float*)d_in[3];
    const float* br = (const float*)d_in[4];
    float* out = (float*)d_out;

    bsq_fused<<<BLOCKS, 128, 0, stream>>>(x, Wp, bp, Wr, br, out);
}

// Round 9
// 74.645 us; speedup vs baseline: 1.6328x; 1.6328x over previous
//
#include <hip/hip_runtime.h>
#include <stdint.h>

// Fused BSQ: recon = sign(x @ Wp + bp) @ Wr + br   (L2-normalize is sign-invariant)
// x: [65536][512] f32, Wp: [512][16], bp: [16], Wr: [16][512], br: [512]
//
// Round-9 = round-7 skeleton + three fixes (round-8's waves_per_eu pin regressed):
//  - Recon of rows 0..15 interleaved into the dot-chunks of rows 16..31:
//    stores fill the WAITV stall shadows, read+write streams overlap.
//    vmcnt counts include the interleaved stores (in-order retirement);
//    a one-time WAITV(0) after the mid-barrier decouples the counts from
//    the weight-load instruction count. CFENCE pins store-after-stage order.
//  - zp transposed to [row][wave][d]: writes hit 16 distinct banks, reads are
//    4-way broadcast (free) -> kills round-7's 3.7M bank conflicts.
//  - LDS 33 -> 24.5 KB (6 blocks/CU capacity).
//  - __launch_bounds__(256,2), natural allocation (rounds 5/8 proved pinning
//    spills). Reference signs are f64-exact: rounds 1-8 absmax 0.0.

#define ROWS   65536
#define TILE   32
#define BLOCKS (ROWS / TILE)   // 2048
#define TAU    1e-3f

#define BAR()    asm volatile("s_waitcnt lgkmcnt(0)\n\ts_barrier" ::: "memory")
#define WAITV(N) asm volatile("s_waitcnt vmcnt(" #N ")" ::: "memory")
#define WAITL()  asm volatile("s_waitcnt lgkmcnt(0)" ::: "memory")
#define CFENCE() asm volatile("" ::: "memory")   // compiler-only fence

typedef const __attribute__((address_space(1))) void* gas1_t;
typedef __attribute__((address_space(3))) void*       las3_t;

__global__ __launch_bounds__(256, 2)
void bsq_fused(const float* __restrict__ x,
               const float* __restrict__ Wp,
               const float* __restrict__ bp,
               const float* __restrict__ Wr,
               const float* __restrict__ br,
               float* __restrict__ out)
{
    const int tid = threadIdx.x;
    const int w   = tid >> 6;      // wave 0..3: c-quarter
    const int l   = tid & 63;
    const int cg  = l >> 4;        // 0..3
    const int dg  = l & 15;        // 0..15: this lane's d

    __shared__ __align__(16) float  xl[4 * 1024];    // 16 KB ring: 4 slots x 2 rows
    __shared__ __align__(16) float  zp[TILE][4][16]; // 8 KB: [row][wave][d]
    __shared__ __align__(16) double zb64[4][16];     // fixup exchange

    // ---- phase-A weights (oldest VMEM; drained by chunk-0's WAITV) ----
    float wp[32];                  // wp[4j+e] = Wp[w*128 + j*16 + cg*4 + e][dg]
#pragma unroll
    for (int j = 0; j < 8; ++j)
#pragma unroll
        for (int e = 0; e < 4; ++e)
            wp[4 * j + e] = Wp[(w * 128 + j * 16 + cg * 4 + e) * 16 + dg];
    const float bpf = bp[dg];

    const int row0 = blockIdx.x * TILE;
    // staging source: lane covers row-parity (l>>5), floats w*128+(l&31)*4
    const float* xsrc = x + (size_t)row0 * 512 + (size_t)(l >> 5) * 512
                          + w * 128 + (l & 31) * 4;

    auto stage = [&](int s) {      // rows 2s,2s+1: wave's 1 KB region, 1 DMA
        __builtin_amdgcn_global_load_lds(
            (gas1_t)(xsrc + (size_t)(2 * s) * 512),
            (las3_t)(&xl[(s & 3) * 1024 + w * 256]), 16, 0, 0);
    };

    auto dot_row = [&](int s, int p) {
        const float* bx = &xl[(s & 3) * 1024 + w * 256 + p * 128 + cg * 4];
        float4 xr[8];
#pragma unroll
        for (int j = 0; j < 8; ++j) xr[j] = *(const float4*)(bx + j * 16);
        float a0 = 0.f, a1 = 0.f, a2 = 0.f, a3 = 0.f;
#pragma unroll
        for (int j = 0; j < 8; ++j) {
            a0 = fmaf(xr[j].x, wp[4 * j + 0], a0);
            a1 = fmaf(xr[j].y, wp[4 * j + 1], a1);
            a2 = fmaf(xr[j].z, wp[4 * j + 2], a2);
            a3 = fmaf(xr[j].w, wp[4 * j + 3], a3);
        }
        float a = (a0 + a1) + (a2 + a3);
        a += __shfl_xor(a, 16, 64);    // full in-wave cg reduce (bits 4,5)
        a += __shfl_xor(a, 32, 64);
        if (l < 16) zp[2 * s + p][w][l] = a;   // 16 writers -> 16 banks, free
    };

    // ========== Phase A first half: rows 0..15 (pure dots) ==========
#pragma unroll
    for (int s = 0; s < 4; ++s) stage(s);
#pragma unroll 1
    for (int c = 0; c < 8; ++c) {
        WAITV(3);                  // oldest slot's DMA retired
        dot_row(c, 0); dot_row(c, 1);
        WAITL();                   // slot's ds_reads retired -> reusable
        stage(c + 4);              // rows 8+2c..9+2c
    }
    BAR();                         // zp rows 0..15 visible (lgkm-only)

    // ---- phase-B weights (wp stays live only through second half) ----
    float2 wr2[16];
    const float2* Wr2 = (const float2*)Wr;
#pragma unroll
    for (int d = 0; d < 16; ++d) wr2[d] = Wr2[d * 256 + tid];
    const float2 br2v = ((const float2*)br)[tid];
    WAITV(0);   // one-time drain: weight loads + stages 8..11 all retired
                // -> second-half vmcnt counts depend only on our stage/stores

    uint32_t amb = 0;              // block-uniform ambiguity mask
    auto recon_row = [&](int r) {
        const float z = zp[r][0][dg] + zp[r][1][dg]
                      + zp[r][2][dg] + zp[r][3][dg] + bpf;
        if (__ballot(fabsf(z) < TAU)) amb |= (1u << r);
        const int m = (int)(__ballot(z >= 0.0f) & 0xFFFFull);
        float ox = br2v.x, oy = br2v.y;
#pragma unroll
        for (int d = 0; d < 16; ++d) {
            const float s = ((m >> d) & 1) ? 1.0f : -1.0f;
            ox = fmaf(s, wr2[d].x, ox);
            oy = fmaf(s, wr2[d].y, oy);
        }
        ((float2*)out)[(size_t)(row0 + r) * 256 + tid] = make_float2(ox, oy);
    };

    // == Phase A second half (rows 16..31) interleaved with recon rows 0..15 ==
    // chunks 8..11: slot data already drained by WAITV(0); 3 vmem ops/chunk
    // (stage + 2 stores), order pinned stage-before-stores by CFENCE.
#pragma unroll 1
    for (int c = 8; c < 12; ++c) {
        dot_row(c, 0); dot_row(c, 1);
        WAITL();
        stage(c + 4);              // rows 24+2(c-8)..
        CFENCE();
        recon_row(2 * (c - 8)); recon_row(2 * (c - 8) + 1);
    }
    // chunks 12..15: need stage(c) issued at chunk c-4.
    // ops after stage(12): 2 stores (c8) + 3x3 (c9..11) = 11 -> WAITV(11); etc.
    WAITV(11); dot_row(12, 0); dot_row(12, 1); recon_row(8);  recon_row(9);
    WAITV(10); dot_row(13, 0); dot_row(13, 1); recon_row(10); recon_row(11);
    WAITV(9);  dot_row(14, 0); dot_row(14, 1); recon_row(12); recon_row(13);
    WAITV(8);  dot_row(15, 0); dot_row(15, 1); recon_row(14); recon_row(15);

    BAR();                         // zp rows 16..31 visible

    // ============ Phase B tail: recon rows 16..31 ============
#pragma unroll 2
    for (int r = 16; r < TILE; ++r) recon_row(r);

    // ===== Fixup: rare exact-f64 redo; uniform loop, matched barriers =====
    const double bpd = (double)bpf;
#pragma unroll 1
    while (amb) {
        const int r = __ffs(amb) - 1;
        amb &= amb - 1;
        const int row = row0 + r;

        const float* xp = x + (size_t)row * 512 + w * 128 + cg * 4;
        double ad = 0.0;
#pragma unroll
        for (int j = 0; j < 8; ++j) {
            const float4 xf = *(const float4*)(xp + j * 16);
#pragma unroll
            for (int e = 0; e < 4; ++e) {
                const float wpe = Wp[(w * 128 + j * 16 + cg * 4 + e) * 16 + dg];
                const float xe  = e == 0 ? xf.x : e == 1 ? xf.y
                               : e == 2 ? xf.z : xf.w;
                ad = fma((double)xe, (double)wpe, ad);
            }
        }
        ad += __shfl_xor(ad, 16, 64);
        ad += __shfl_xor(ad, 32, 64);
        if (l < 16) zb64[w][l] = ad;
        BAR();
        const double zd = (zb64[0][dg] + zb64[1][dg])
                        + (zb64[2][dg] + zb64[3][dg]) + bpd;
        const int m = (int)(__ballot(zd >= 0.0) & 0xFFFFull);
        BAR();   // zb64 reads retired before next fixup row's rewrite

        float ox = br2v.x, oy = br2v.y;
#pragma unroll
        for (int d = 0; d < 16; ++d) {
            const float s = ((m >> d) & 1) ? 1.0f : -1.0f;
            ox = fmaf(s, wr2[d].x, ox);
            oy = fmaf(s, wr2[d].y, oy);
        }
        ((float2*)out)[(size_t)row * 256 + tid] = make_float2(ox, oy);
    }
}

extern "C" void kernel_launch(void* const* d_in, const int* in_sizes, int n_in,
                              void* d_out, int out_size, void* d_ws, size_t ws_size,
                              hipStream_t stream) {
    const float* x  = (const float*)d_in[0];
    const float* Wp = (const float*)d_in[1];
    const float* bp = (const float*)d_in[2];
    const float* Wr = (const float*)d_in[3];
    const float* br = (const float*)d_in[4];
    float* out = (float*)d_out;

    bsq_fused<<<BLOCKS, 256, 0, stream>>>(x, Wp, bp, Wr, br, out);
}

// Round 10
// 64.657 us; speedup vs baseline: 1.8850x; 1.1545x over previous
//
#include <hip/hip_runtime.h>
#include <stdint.h>

// Fused BSQ: recon = sign(x @ Wp + bp) @ Wr + br   (L2-normalize is sign-invariant)
// x: [65536][512] f32, Wp: [512][16], bp: [16], Wr: [16][512], br: [512]
//
// Round-10 = round-9 skeleton + three fixes:
//  - pk-math: dot and recon use v_pk_fma_f32 via v2f (halves dominant VALU).
//  - chunk order: reads+FMAs -> WAITL -> stage -> shuffles+zp-write. The
//    lgkmcnt(0) now covers only the (mostly-retired) ds_reads; the shuffles
//    (ds ops!) no longer sit on the stage path (round-9 bug: WAITL after
//    shuffles serialized ~50cyc/chunk of swizzle latency).
//  - zp transposed to [row][d][wave]: phase-B reduce = 1 ds_read_b128 + 3
//    adds (2-way bank aliases only = free).
//  - DMA ring (4 slots x 2 rows), per-wave counted vmcnt, recon of rows
//    0..15 interleaved into dot-chunks of rows 16..31, barrier-free phase B,
//    post-loop uniform f64 fixup. Reference signs are f64-exact (r1-9
//    absmax 0.0). __launch_bounds__(256,2), natural regalloc (pins spill).

#define ROWS   65536
#define TILE   32
#define BLOCKS (ROWS / TILE)   // 2048
#define TAU    1e-3f

#define BAR()    asm volatile("s_waitcnt lgkmcnt(0)\n\ts_barrier" ::: "memory")
#define WAITV(N) asm volatile("s_waitcnt vmcnt(" #N ")" ::: "memory")
#define WAITL()  asm volatile("s_waitcnt lgkmcnt(0)" ::: "memory")
#define CFENCE() asm volatile("" ::: "memory")   // compiler-only fence

typedef const __attribute__((address_space(1))) void* gas1_t;
typedef __attribute__((address_space(3))) void*       las3_t;
typedef float v2f __attribute__((ext_vector_type(2)));

__global__ __launch_bounds__(256, 2)
void bsq_fused(const float* __restrict__ x,
               const float* __restrict__ Wp,
               const float* __restrict__ bp,
               const float* __restrict__ Wr,
               const float* __restrict__ br,
               float* __restrict__ out)
{
    const int tid = threadIdx.x;
    const int w   = tid >> 6;      // wave 0..3: c-quarter
    const int l   = tid & 63;
    const int cg  = l >> 4;        // 0..3
    const int dg  = l & 15;        // 0..15: this lane's d

    __shared__ __align__(16) float  xl[4 * 1024];     // 16 KB ring: 4 slots x 2 rows
    __shared__ __align__(16) float  zp[TILE][16][4];  // 8 KB: [row][d][wave]
    __shared__ __align__(16) double zb64[4][16];      // fixup exchange

    // ---- phase-A weights as v2f pairs (32 scalar loads, 32 VGPR) ----
    // wpA[j] = (Wp[c0][dg], Wp[c0+1][dg]); wpB[j] = (Wp[c0+2][dg], Wp[c0+3][dg])
    // where c0 = w*128 + j*16 + cg*4
    v2f wpA[8], wpB[8];
#pragma unroll
    for (int j = 0; j < 8; ++j) {
        const float* wj = Wp + (w * 128 + j * 16 + cg * 4) * 16 + dg;
        wpA[j] = (v2f){ wj[0],  wj[16] };
        wpB[j] = (v2f){ wj[32], wj[48] };
    }
    const float bpf = bp[dg];

    const int row0 = blockIdx.x * TILE;
    // staging source: lane covers row-parity (l>>5), floats w*128+(l&31)*4
    const float* xsrc = x + (size_t)row0 * 512 + (size_t)(l >> 5) * 512
                          + w * 128 + (l & 31) * 4;

    auto stage = [&](int s) {      // rows 2s,2s+1: wave's 1 KB region, 1 DMA
        __builtin_amdgcn_global_load_lds(
            (gas1_t)(xsrc + (size_t)(2 * s) * 512),
            (las3_t)(&xl[(s & 3) * 1024 + w * 256]), 16, 0, 0);
    };

    auto dot_part = [&](int s, int p, v2f& accA, v2f& accB) {
        const float* bx = &xl[(s & 3) * 1024 + w * 256 + p * 128 + cg * 4];
        float4 xr[8];
#pragma unroll
        for (int j = 0; j < 8; ++j) xr[j] = *(const float4*)(bx + j * 16);
        accA = (v2f){0.f, 0.f};  accB = (v2f){0.f, 0.f};
#pragma unroll
        for (int j = 0; j < 8; ++j) {
            accA += (v2f){ xr[j].x, xr[j].y } * wpA[j];   // v_pk_fma_f32
            accB += (v2f){ xr[j].z, xr[j].w } * wpB[j];
        }
    };
    auto fin_part = [&](int r, v2f accA, v2f accB) {
        float a = (accA.x + accA.y) + (accB.x + accB.y);
        a += __shfl_xor(a, 16, 64);    // reduce over cg (lane bits 4,5)
        a += __shfl_xor(a, 32, 64);
        if (l < 16) zp[r][l][w] = a;   // 2-way bank alias = free
    };

    // ========== Phase A first half: rows 0..15 (pure dots) ==========
#pragma unroll
    for (int s = 0; s < 4; ++s) stage(s);
#pragma unroll 1
    for (int c = 0; c < 8; ++c) {
        WAITV(3);                  // oldest slot's DMA retired
        v2f aA0, aB0, aA1, aB1;
        dot_part(c, 0, aA0, aB0);
        dot_part(c, 1, aA1, aB1);
        CFENCE();
        WAITL();                   // only ds_reads outstanding here (cheap)
        stage(c + 4);              // refill slot 4 chunks ahead
        CFENCE();
        fin_part(2 * c, aA0, aB0);
        fin_part(2 * c + 1, aA1, aB1);
    }
    BAR();                         // zp rows 0..15 visible (lgkm-only)

    // ---- phase-B weights (v2f; wp stays live through second half) ----
    v2f wrv[16];
    const float2* Wr2 = (const float2*)Wr;
#pragma unroll
    for (int d = 0; d < 16; ++d) {
        const float2 t = Wr2[d * 256 + tid];
        wrv[d] = (v2f){ t.x, t.y };
    }
    const float2 brt = ((const float2*)br)[tid];
    const v2f br2v = (v2f){ brt.x, brt.y };
    WAITV(0);   // one-time drain: weight loads + stages 8..11 retired ->
                // second-half vmcnt counts depend only on our stage/stores

    uint32_t amb = 0;              // block-uniform ambiguity mask
    auto recon_row = [&](int r) {
        const float4 q = *(const float4*)&zp[r][dg][0];   // 1 b128, conflict-free
        const float  z = (q.x + q.y) + (q.z + q.w) + bpf;
        if (__ballot(fabsf(z) < TAU)) amb |= (1u << r);
        const int m = (int)(__ballot(z >= 0.0f) & 0xFFFFull);
        v2f o = br2v;
#pragma unroll
        for (int d = 0; d < 16; ++d) {
            const float s = ((m >> d) & 1) ? 1.0f : -1.0f;
            o += (v2f){ s, s } * wrv[d];                  // v_pk_fma_f32
        }
        ((float2*)out)[(size_t)(row0 + r) * 256 + tid] = make_float2(o.x, o.y);
    };

    // == Phase A second half (rows 16..31) interleaved with recon rows 0..15 ==
    // vmem order per chunk 8..11: stage, store, store (pinned by CFENCE).
#pragma unroll 1
    for (int c = 8; c < 12; ++c) {
        v2f aA0, aB0, aA1, aB1;
        dot_part(c, 0, aA0, aB0);       // slot data pre-drained by WAITV(0)
        dot_part(c, 1, aA1, aB1);
        CFENCE();
        WAITL();
        stage(c + 4);                   // rows 24..31 into slots 12..15
        CFENCE();
        fin_part(2 * c, aA0, aB0);
        fin_part(2 * c + 1, aA1, aB1);
        recon_row(2 * (c - 8));
        recon_row(2 * (c - 8) + 1);
    }
    // chunks 12..15: stage(c) was issued in chunk c-4.
    // ops after stage(12): 2 stores (c8) + 3x3 (c9..11) = 11 -> WAITV(11); etc.
    {
        v2f aA0, aB0, aA1, aB1;
        WAITV(11);
        dot_part(12, 0, aA0, aB0); dot_part(12, 1, aA1, aB1);
        fin_part(24, aA0, aB0); fin_part(25, aA1, aB1);
        recon_row(8);  recon_row(9);
        WAITV(10);
        dot_part(13, 0, aA0, aB0); dot_part(13, 1, aA1, aB1);
        fin_part(26, aA0, aB0); fin_part(27, aA1, aB1);
        recon_row(10); recon_row(11);
        WAITV(9);
        dot_part(14, 0, aA0, aB0); dot_part(14, 1, aA1, aB1);
        fin_part(28, aA0, aB0); fin_part(29, aA1, aB1);
        recon_row(12); recon_row(13);
        WAITV(8);
        dot_part(15, 0, aA0, aB0); dot_part(15, 1, aA1, aB1);
        fin_part(30, aA0, aB0); fin_part(31, aA1, aB1);
        recon_row(14); recon_row(15);
    }
    BAR();                         // zp rows 16..31 visible

    // ============ Phase B tail: recon rows 16..31 ============
#pragma unroll 2
    for (int r = 16; r < TILE; ++r) recon_row(r);

    // ===== Fixup: rare exact-f64 redo; uniform loop, matched barriers =====
    const double bpd = (double)bpf;
#pragma unroll 1
    while (amb) {
        const int r = __ffs(amb) - 1;
        amb &= amb - 1;
        const int row = row0 + r;

        const float* xp = x + (size_t)row * 512 + w * 128 + cg * 4;
        double ad = 0.0;
#pragma unroll
        for (int j = 0; j < 8; ++j) {
            const float4 xf = *(const float4*)(xp + j * 16);
#pragma unroll
            for (int e = 0; e < 4; ++e) {
                const float wpe = Wp[(w * 128 + j * 16 + cg * 4 + e) * 16 + dg];
                const float xe  = e == 0 ? xf.x : e == 1 ? xf.y
                               : e == 2 ? xf.z : xf.w;
                ad = fma((double)xe, (double)wpe, ad);
            }
        }
        ad += __shfl_xor(ad, 16, 64);
        ad += __shfl_xor(ad, 32, 64);
        if (l < 16) zb64[w][l] = ad;
        BAR();
        const double zd = (zb64[0][dg] + zb64[1][dg])
                        + (zb64[2][dg] + zb64[3][dg]) + bpd;
        const int m = (int)(__ballot(zd >= 0.0) & 0xFFFFull);
        BAR();   // zb64 reads retired before next fixup row's rewrite

        v2f o = br2v;
#pragma unroll
        for (int d = 0; d < 16; ++d) {
            const float s = ((m >> d) & 1) ? 1.0f : -1.0f;
            o += (v2f){ s, s } * wrv[d];
        }
        ((float2*)out)[(size_t)row * 256 + tid] = make_float2(o.x, o.y);
    }
}

extern "C" void kernel_launch(void* const* d_in, const int* in_sizes, int n_in,
                              void* d_out, int out_size, void* d_ws, size_t ws_size,
                              hipStream_t stream) {
    const float* x  = (const float*)d_in[0];
    const float* Wp = (const float*)d_in[1];
    const float* bp = (const float*)d_in[2];
    const float* Wr = (const float*)d_in[3];
    const float* br = (const float*)d_in[4];
    float* out = (float*)d_out;

    bsq_fused<<<BLOCKS, 256, 0, stream>>>(x, Wp, bp, Wr, br, out);
}